// Round 1
// baseline (39.756 us; speedup 1.0000x reference)
//
#include <hip/hip_runtime.h>
#include <math.h>

// Problem constants
#define B_TOT 256
#define N_N   8
#define P_P   1152
#define J_J   160        // L*O = 10*16
#define K_K   9216       // N_N * P_P
#define L_L   10
#define O_O   16

// GEMM tiling
#define BM       64      // batch rows per block
#define S_SLICES 64      // split-K slices
#define KL       144     // K per slice (K_K / S_SLICES)
#define KB       48      // K per LDS step (KL / 3)

// ---------------------------------------------------------------------------
// Kernel 1: transform W (1,P,L,O,N) -> Bmat[k][j], k = n*P + p, j = l*16+o.
// W flat:  [p][l][o][n] = p*1280 + j*8 + n   (j = l*16+o)
// Bmat:    [(n*1152 + p)*160 + j]
// ---------------------------------------------------------------------------
__global__ __launch_bounds__(256) void transform_w(const float* __restrict__ W,
                                                   float* __restrict__ Bmat) {
    const int p = blockIdx.x;
    __shared__ float w[1280];
    const float* src = W + (size_t)p * 1280;
    for (int i = threadIdx.x; i < 1280; i += 256) w[i] = src[i];
    __syncthreads();
    for (int i = threadIdx.x; i < 1280; i += 256) {
        const int n = i / 160;
        const int j = i - n * 160;
        Bmat[((size_t)n * P_P + p) * J_J + j] = w[j * 8 + n];
    }
}

// ---------------------------------------------------------------------------
// Kernel 2: split-K SGEMM.  s[b][j] = sum_k x[b][k] * Bmat[k][j]
// grid = (4 b-tiles, 64 slices), 256 threads.
// Each thread: 4 b-rows x 10 j-cols (j strided by 16) = 40 accumulators.
// Writes deterministic partials: part[slice][b][j].
// ---------------------------------------------------------------------------
__global__ __launch_bounds__(256) void gemm_splitk(const float* __restrict__ x,
                                                   const float* __restrict__ Bmat,
                                                   float* __restrict__ part) {
    const int btile = blockIdx.x;      // 0..3
    const int slice = blockIdx.y;      // 0..63
    const int tid   = threadIdx.x;
    const int jt    = tid & 15;        // j = jt + 16*q
    const int bt    = tid >> 4;        // b = b0 + bt*4 + bi
    const int b0    = btile * BM;

    __shared__ __align__(16) float As[KB][BM + 4];   // [kk][bb], row stride 68 (272B, 16B-mult)
    __shared__ __align__(16) float Bs[KB][J_J];      // [kk][j]

    float acc[4][10];
    #pragma unroll
    for (int bi = 0; bi < 4; ++bi)
        #pragma unroll
        for (int q = 0; q < 10; ++q) acc[bi][q] = 0.0f;

    const int k0 = slice * KL;

    for (int ks = 0; ks < KL / KB; ++ks) {
        const int kb = k0 + ks * KB;
        __syncthreads();

        // Stage A: x[(b0+bb)*K + kb + kk] -> As[kk][bb]   (transposed store)
        #pragma unroll
        for (int it = 0; it < (BM * KB) / 256; ++it) {
            const int idx = tid + it * 256;
            const int bb  = idx / KB;
            const int kk  = idx - bb * KB;
            As[kk][bb] = x[(size_t)(b0 + bb) * K_K + kb + kk];
        }

        // Stage B: Bmat rows kb..kb+KB fully contiguous -> Bs, float4
        {
            const float4* src = reinterpret_cast<const float4*>(Bmat + (size_t)kb * J_J);
            float4* dst = reinterpret_cast<float4*>(&Bs[0][0]);
            for (int idx = tid; idx < (KB * J_J) / 4; idx += 256)
                dst[idx] = src[idx];
        }

        __syncthreads();

        // Compute
        #pragma unroll 4
        for (int kk = 0; kk < KB; ++kk) {
            const float4 a = *reinterpret_cast<const float4*>(&As[kk][bt * 4]);
            float w[10];
            #pragma unroll
            for (int q = 0; q < 10; ++q) w[q] = Bs[kk][jt + 16 * q];
            const float a0 = a.x, a1 = a.y, a2 = a.z, a3 = a.w;
            #pragma unroll
            for (int q = 0; q < 10; ++q) {
                acc[0][q] = fmaf(a0, w[q], acc[0][q]);
                acc[1][q] = fmaf(a1, w[q], acc[1][q]);
                acc[2][q] = fmaf(a2, w[q], acc[2][q]);
                acc[3][q] = fmaf(a3, w[q], acc[3][q]);
            }
        }
    }

    // Write partials: part[(slice*B_TOT + b)*J + j]
    float* pbase = part + (size_t)slice * B_TOT * J_J;
    #pragma unroll
    for (int bi = 0; bi < 4; ++bi) {
        const int b = b0 + bt * 4 + bi;
        #pragma unroll
        for (int q = 0; q < 10; ++q)
            pbase[(size_t)b * J_J + jt + 16 * q] = acc[bi][q];
    }
}

// ---------------------------------------------------------------------------
// Kernel 3: reduce partials over slices + squash (norm over L axis) -> out
// v[b,l,o] = s * mag / (1 + msq),  msq = sum_l s[b,l,o]^2, mag = sqrt(msq)
// ---------------------------------------------------------------------------
__global__ __launch_bounds__(256) void reduce_squash(const float* __restrict__ part,
                                                     float* __restrict__ out) {
    const int b = blockIdx.x;
    const int j = threadIdx.x;
    __shared__ float sld[J_J];
    float s = 0.0f;
    if (j < J_J) {
        #pragma unroll 8
        for (int si = 0; si < S_SLICES; ++si)
            s += part[((size_t)si * B_TOT + b) * J_J + j];
        sld[j] = s;
    }
    __syncthreads();
    if (j < J_J) {
        const int o = j & 15;
        float msq = 0.0f;
        #pragma unroll
        for (int l = 0; l < L_L; ++l) {
            const float v = sld[l * 16 + o];
            msq = fmaf(v, v, msq);
        }
        const float mag = sqrtf(msq);
        out[(size_t)b * J_J + j] = s * (mag / (1.0f + msq));
    }
}

// ---------------------------------------------------------------------------
extern "C" void kernel_launch(void* const* d_in, const int* in_sizes, int n_in,
                              void* d_out, int out_size, void* d_ws, size_t ws_size,
                              hipStream_t stream) {
    const float* x = (const float*)d_in[0];   // (256, 8, 1152)
    const float* W = (const float*)d_in[1];   // (1, 1152, 10, 16, 8)
    float* out  = (float*)d_out;              // (256, 10, 16)

    float* Bmat = (float*)d_ws;                                   // K_K * J_J floats
    float* part = Bmat + (size_t)K_K * J_J;                       // S * B * J floats

    transform_w<<<P_P, 256, 0, stream>>>(W, Bmat);

    dim3 grid(B_TOT / BM, S_SLICES);
    gemm_splitk<<<grid, 256, 0, stream>>>(x, Bmat, part);

    reduce_squash<<<B_TOT, 256, 0, stream>>>(part, out);
}

// Round 2
// 36.755 us; speedup vs baseline: 1.0817x; 1.0817x over previous
//
#include <hip/hip_runtime.h>
#include <math.h>

// Problem constants
#define B_TOT 256
#define N_N   8
#define P_P   1152
#define J_J   160        // L*O
#define K_K   9216       // N_N * P_P
#define L_L   10

// GEMM config
#define S_SLICES 36      // split-K slices
#define KSTEPS   8       // MFMA k-steps per slice (8 * 32 = 256 k)

typedef __attribute__((ext_vector_type(8))) short short8;   // 8 x bf16 (4 VGPRs)
typedef __attribute__((ext_vector_type(4))) float f32x4;

__device__ __forceinline__ short f2bf(float f) {
    unsigned u = __builtin_bit_cast(unsigned, f);
    unsigned r = (u + 0x7fffu + ((u >> 16) & 1u)) >> 16;   // RNE
    return (short)r;
}

// ---------------------------------------------------------------------------
// Kernel 1: W (1,P,L,O,N) fp32 -> Bt[j][k] bf16, j = l*16+o, k = n*1152+p.
// W flat: [p][j][n] = p*1280 + j*8 + n.
// Tile: 128 p x 4 j (x all 8 n) per block; LDS transpose.
// Reads: full 128B lines, each W line read exactly once. Writes contiguous.
// ---------------------------------------------------------------------------
__global__ __launch_bounds__(256) void transform_w(const float* __restrict__ W,
                                                   short* __restrict__ Bt) {
    const int p0 = blockIdx.x * 128;
    const int j0 = blockIdx.y * 4;
    const int tid = threadIdx.x;
    __shared__ float lds[128][33];   // +1 pad: bank = (p + f) % 32

    // read: 128 p x 32 floats (4 j * 8 n), contiguous 128B per p
    #pragma unroll
    for (int it = 0; it < 16; ++it) {
        const int idx = it * 256 + tid;
        const int p = idx >> 5;
        const int f = idx & 31;
        lds[p][f] = W[(size_t)(p0 + p) * 1280 + j0 * 8 + f];
    }
    __syncthreads();
    // write: Bt[(j0+dj)*K + n*1152 + p0 + pp], contiguous in pp
    #pragma unroll
    for (int it = 0; it < 16; ++it) {
        const int idx = it * 256 + tid;
        const int c  = idx >> 7;    // 0..31 = dj*8 + n
        const int pp = idx & 127;
        const int dj = c >> 3;
        const int n  = c & 7;
        Bt[(size_t)(j0 + dj) * K_K + n * P_P + p0 + pp] = f2bf(lds[pp][c]);
    }
}

// ---------------------------------------------------------------------------
// Kernel 2: split-K MFMA GEMM.  s[b][j] = sum_k x[b][k] * Bt[j][k]
// grid = (16 b-tiles, 36 slices), 64 threads (1 wave, no barriers).
// Wave: 16 b-rows x 160 j (10 MFMA tiles) x 256 k.
// A-frag: row = lane&15 (b), k = (lane>>4)*8 + e  -> 8 contiguous fp32 from x,
//         converted to bf16 in-register.
// B-frag: row = lane&15 (j), same k pattern -> one 16B load from Bt.
// D: col(j) = lane&15, row(b) = (lane>>4)*4 + reg.
// Partials: part[b][slice][j] fp32 (deterministic).
// ---------------------------------------------------------------------------
__global__ __launch_bounds__(64) void gemm_mfma(const float* __restrict__ x,
                                                const short* __restrict__ Bt,
                                                float* __restrict__ part) {
    const int lane  = threadIdx.x;
    const int b0    = blockIdx.x * 16;
    const int slice = blockIdx.y;
    const int m  = lane & 15;
    const int kq = lane >> 4;          // 0..3

    const float* xrow = x  + (size_t)(b0 + m) * K_K + slice * 256 + kq * 8;
    const short* brow = Bt + (size_t)m * K_K        + slice * 256 + kq * 8;

    f32x4 acc[10];
    #pragma unroll
    for (int jt = 0; jt < 10; ++jt) acc[jt] = f32x4{0.f, 0.f, 0.f, 0.f};

    #pragma unroll 2
    for (int ks = 0; ks < KSTEPS; ++ks) {
        const f32x4 a0 = *reinterpret_cast<const f32x4*>(xrow + ks * 32);
        const f32x4 a1 = *reinterpret_cast<const f32x4*>(xrow + ks * 32 + 4);
        short8 af;
        af[0] = f2bf(a0.x); af[1] = f2bf(a0.y); af[2] = f2bf(a0.z); af[3] = f2bf(a0.w);
        af[4] = f2bf(a1.x); af[5] = f2bf(a1.y); af[6] = f2bf(a1.z); af[7] = f2bf(a1.w);
        #pragma unroll
        for (int jt = 0; jt < 10; ++jt) {
            const short8 bf = *reinterpret_cast<const short8*>(brow + (size_t)jt * 16 * K_K + ks * 32);
            acc[jt] = __builtin_amdgcn_mfma_f32_16x16x32_bf16(af, bf, acc[jt], 0, 0, 0);
        }
    }

    // epilogue
    #pragma unroll
    for (int jt = 0; jt < 10; ++jt) {
        #pragma unroll
        for (int r = 0; r < 4; ++r) {
            const int b = b0 + kq * 4 + r;
            part[((size_t)b * S_SLICES + slice) * J_J + jt * 16 + m] = acc[jt][r];
        }
    }
}

// ---------------------------------------------------------------------------
// Kernel 3: reduce partials over slices + squash (norm over L axis) -> out
// part[b][si][j]: per-b strip is 36*160 floats contiguous.
// ---------------------------------------------------------------------------
__global__ __launch_bounds__(192) void reduce_squash(const float* __restrict__ part,
                                                     float* __restrict__ out) {
    const int b = blockIdx.x;
    const int j = threadIdx.x;
    __shared__ float sld[J_J];
    float s = 0.0f;
    if (j < J_J) {
        const float* pb = part + (size_t)b * S_SLICES * J_J + j;
        #pragma unroll 6
        for (int si = 0; si < S_SLICES; ++si)
            s += pb[si * J_J];
        sld[j] = s;
    }
    __syncthreads();
    if (j < J_J) {
        const int o = j & 15;
        float msq = 0.0f;
        #pragma unroll
        for (int l = 0; l < L_L; ++l) {
            const float v = sld[l * 16 + o];
            msq = fmaf(v, v, msq);
        }
        const float mag = sqrtf(msq);
        out[(size_t)b * J_J + j] = s * (mag / (1.0f + msq));
    }
}

// ---------------------------------------------------------------------------
extern "C" void kernel_launch(void* const* d_in, const int* in_sizes, int n_in,
                              void* d_out, int out_size, void* d_ws, size_t ws_size,
                              hipStream_t stream) {
    const float* x = (const float*)d_in[0];   // (256, 8, 1152)
    const float* W = (const float*)d_in[1];   // (1, 1152, 10, 16, 8)
    float* out = (float*)d_out;               // (256, 10, 16)

    short* Bt  = (short*)d_ws;                                  // J_J * K_K bf16
    float* part = (float*)((char*)d_ws + (size_t)J_J * K_K * 2); // B*S*J fp32

    dim3 gt(P_P / 128, J_J / 4);
    transform_w<<<gt, 256, 0, stream>>>(W, Bt);

    dim3 gg(B_TOT / 16, S_SLICES);
    gemm_mfma<<<gg, 64, 0, stream>>>(x, Bt, part);

    reduce_squash<<<B_TOT, 192, 0, stream>>>(part, out);
}

// Round 3
// 26.784 us; speedup vs baseline: 1.4843x; 1.3723x over previous
//
#include <hip/hip_runtime.h>
#include <math.h>

// Problem constants
#define B_TOT 256
#define N_N   8
#define P_P   1152
#define J_J   160        // L*O
#define K_K   9216       // N_N * P_P
#define L_L   10

// GEMM config
#define S_SLICES 36      // split-K slices (256 k each, 8 MFMA k-steps)
#define KSTEPS   8

typedef __attribute__((ext_vector_type(8))) short short8;   // 8 x bf16 (4 VGPRs)
typedef __attribute__((ext_vector_type(4))) float f32x4;

__device__ __forceinline__ short f2bf(float f) {
    unsigned u = __builtin_bit_cast(unsigned, f);
    unsigned r = (u + 0x7fffu + ((u >> 16) & 1u)) >> 16;   // RNE
    return (short)r;
}

// ---------------------------------------------------------------------------
// Kernel 1: W (1,P,L,O,N) fp32 -> Bt[j][k] bf16, j = l*16+o, k = n*1152+p.
// W flat: [p][j][n] = p*1280 + j*8 + n.
// Tile: 128 p x 4 j (x all 8 n) per block; LDS transpose.
// ---------------------------------------------------------------------------
__global__ __launch_bounds__(256) void transform_w(const float* __restrict__ W,
                                                   short* __restrict__ Bt) {
    const int p0 = blockIdx.x * 128;
    const int j0 = blockIdx.y * 4;
    const int tid = threadIdx.x;
    __shared__ float lds[128][33];   // +1 pad

    #pragma unroll
    for (int it = 0; it < 16; ++it) {
        const int idx = it * 256 + tid;
        const int p = idx >> 5;
        const int f = idx & 31;
        lds[p][f] = W[(size_t)(p0 + p) * 1280 + j0 * 8 + f];
    }
    __syncthreads();
    #pragma unroll
    for (int it = 0; it < 16; ++it) {
        const int idx = it * 256 + tid;
        const int c  = idx >> 7;    // 0..31 = dj*8 + n
        const int pp = idx & 127;
        const int dj = c >> 3;
        const int n  = c & 7;
        Bt[(size_t)(j0 + dj) * K_K + n * P_P + p0 + pp] = f2bf(lds[pp][c]);
    }
}

// ---------------------------------------------------------------------------
// Kernel 2: split-K MFMA GEMM.  s[b][j] = sum_k x[b][k] * Bt[j][k]
// grid = (16 b-tiles, 36 slices, 5 j-groups), 64 threads (1 wave).
// Wave: 16 b-rows x 32 j (2 MFMA tiles) x 256 k (8 k-steps) = 16 MFMA.
// 2880 waves total (~2.8 waves/SIMD) for latency hiding.
// A-frag: row b = lane&15, k = (lane>>4)*8+e -> two float4 from x, cvt bf16.
// B-frag: row j = jg*32 + jtp*16 + (lane&15), one 16B load from Bt.
// D: col j = lane&15, row b = (lane>>4)*4 + reg   [verified layout]
// Partials: part[b][slice][j] fp32 (deterministic).
// ---------------------------------------------------------------------------
__global__ __launch_bounds__(64) void gemm_mfma(const float* __restrict__ x,
                                                const short* __restrict__ Bt,
                                                float* __restrict__ part) {
    const int bt = blockIdx.x;      // 0..15
    const int kg = blockIdx.y;      // 0..35
    const int jg = blockIdx.z;      // 0..4
    const int lane = threadIdx.x;
    const int m  = lane & 15;
    const int kq = lane >> 4;       // 0..3
    const int b0 = bt * 16;
    const int k0 = kg * 256;

    const float* xrow  = x  + (size_t)(b0 + m) * K_K + k0 + kq * 8;
    const short* brow0 = Bt + (size_t)(jg * 32 + m) * K_K + k0 + kq * 8;
    const short* brow1 = brow0 + (size_t)16 * K_K;

    f32x4 acc0 = {0.f, 0.f, 0.f, 0.f};
    f32x4 acc1 = {0.f, 0.f, 0.f, 0.f};

    #pragma unroll
    for (int ks = 0; ks < KSTEPS; ++ks) {
        const f32x4 a0 = *reinterpret_cast<const f32x4*>(xrow + ks * 32);
        const f32x4 a1 = *reinterpret_cast<const f32x4*>(xrow + ks * 32 + 4);
        short8 af;
        af[0] = f2bf(a0.x); af[1] = f2bf(a0.y); af[2] = f2bf(a0.z); af[3] = f2bf(a0.w);
        af[4] = f2bf(a1.x); af[5] = f2bf(a1.y); af[6] = f2bf(a1.z); af[7] = f2bf(a1.w);
        const short8 bf0 = *reinterpret_cast<const short8*>(brow0 + ks * 32);
        const short8 bf1 = *reinterpret_cast<const short8*>(brow1 + ks * 32);
        acc0 = __builtin_amdgcn_mfma_f32_16x16x32_bf16(af, bf0, acc0, 0, 0, 0);
        acc1 = __builtin_amdgcn_mfma_f32_16x16x32_bf16(af, bf1, acc1, 0, 0, 0);
    }

    // part[b][kg][j]: per-b strip contiguous for the reducer
    #pragma unroll
    for (int r = 0; r < 4; ++r) {
        const int b = b0 + kq * 4 + r;
        float* pb = part + ((size_t)b * S_SLICES + kg) * J_J + jg * 32 + m;
        pb[0]  = acc0[r];
        pb[16] = acc1[r];
    }
}

// ---------------------------------------------------------------------------
// Kernel 3: reduce partials over slices + squash (norm over L axis) -> out
// part[b][si][j]: per-b strip is S_SLICES*160 floats contiguous.
// ---------------------------------------------------------------------------
__global__ __launch_bounds__(192) void reduce_squash(const float* __restrict__ part,
                                                     float* __restrict__ out) {
    const int b = blockIdx.x;
    const int j = threadIdx.x;
    __shared__ float sld[J_J];
    float s = 0.0f;
    if (j < J_J) {
        const float* pb = part + (size_t)b * S_SLICES * J_J + j;
        #pragma unroll 6
        for (int si = 0; si < S_SLICES; ++si)
            s += pb[(size_t)si * J_J];
        sld[j] = s;
    }
    __syncthreads();
    if (j < J_J) {
        const int o = j & 15;
        float msq = 0.0f;
        #pragma unroll
        for (int l = 0; l < L_L; ++l) {
            const float v = sld[l * 16 + o];
            msq = fmaf(v, v, msq);
        }
        const float mag = sqrtf(msq);
        out[(size_t)b * J_J + j] = s * (mag / (1.0f + msq));
    }
}

// ---------------------------------------------------------------------------
extern "C" void kernel_launch(void* const* d_in, const int* in_sizes, int n_in,
                              void* d_out, int out_size, void* d_ws, size_t ws_size,
                              hipStream_t stream) {
    const float* x = (const float*)d_in[0];   // (256, 8, 1152)
    const float* W = (const float*)d_in[1];   // (1, 1152, 10, 16, 8)
    float* out = (float*)d_out;               // (256, 10, 16)

    short* Bt   = (short*)d_ws;                                    // J_J*K_K bf16
    float* part = (float*)((char*)d_ws + (size_t)J_J * K_K * 2);   // B*S*J fp32

    dim3 gt(P_P / 128, J_J / 4);
    transform_w<<<gt, 256, 0, stream>>>(W, Bt);

    dim3 gg(B_TOT / 16, S_SLICES, 5);
    gemm_mfma<<<gg, 64, 0, stream>>>(x, Bt, part);

    reduce_squash<<<B_TOT, 192, 0, stream>>>(part, out);
}